// Round 1
// baseline (46.633 us; speedup 1.0000x reference)
//
#include <hip/hip_runtime.h>

#define E  9
#define B_ 8
#define H_ 224
#define W_ 224
#define C_ 32
// total output elems = 8*224*224*32 = 12,845,056 ; /4 per thread = 3,211,264 threads
#define NTHREADS (B_ * H_ * W_ * (C_ / 4))

__global__ __launch_bounds__(64) void fm_prep(const float* __restrict__ mask,
                                              float* __restrict__ m_out) {
    int t = threadIdx.x;           // single wave of 64
    float v[5];
    float mx = 0.0f;
#pragma unroll
    for (int i = 0; i < 5; ++i) {
        int idx = t + i * 64;
        v[i] = (idx < E * C_) ? fabsf(mask[idx]) : 0.0f;
        mx = fmaxf(mx, v[i]);
    }
#pragma unroll
    for (int off = 32; off >= 1; off >>= 1)
        mx = fmaxf(mx, __shfl_xor(mx, off));
    float inv = 1.0f / (mx + 1e-6f);
#pragma unroll
    for (int i = 0; i < 5; ++i) {
        int idx = t + i * 64;
        if (idx < E * C_) m_out[idx] = v[i] * inv;
    }
}

__global__ __launch_bounds__(256) void fm_main(const float* __restrict__ inp,
                                               const float* __restrict__ kern,
                                               const float* __restrict__ m,
                                               float* __restrict__ out) {
    __shared__ float s_m[E * C_];
    __shared__ float s_k[E * C_];
    {
        int t = threadIdx.x;
        for (int i = t; i < E * C_; i += 256) {
            s_m[i] = m[i];
            s_k[i] = kern[i];
        }
    }
    __syncthreads();

    int gid = blockIdx.x * 256 + threadIdx.x;   // < 3,211,264 (exact grid)
    int cq = (gid & 7) << 2;                    // channel quad start: 0,4,...,28
    int p  = gid >> 3;                          // pixel index
    int w  = p % W_;
    int t2 = p / W_;
    int h  = t2 % H_;
    int b  = t2 / H_;

    // tap order: e=0 center, then (y,x) raster skipping center
    const int dyA[E] = {0, -1, -1, -1, 0, 0, 1, 1, 1};
    const int dxA[E] = {0, -1,  0,  1, -1, 1, -1, 0, 1};

    float dx_[E], dy_[E], dz_[E], dw_[E];
    float n0 = 0.f, n1 = 0.f, n2 = 0.f, n3 = 0.f;   // norm_1 accum
    float s0 = 0.f, s1 = 0.f, s2 = 0.f, s3 = 0.f;   // sum(diff) accum

#pragma unroll
    for (int e = 0; e < E; ++e) {
        int hh = h + dyA[e];
        int ww = w + dxA[e];
        bool ok = ((unsigned)hh < (unsigned)H_) && ((unsigned)ww < (unsigned)W_);
        float tx = 0.f, ty = 0.f, tz = 0.f, tw = 0.f;
        if (ok) {
            int idx = (((b * H_ + hh) * W_ + ww) * C_) + cq;
            float4 t4 = *reinterpret_cast<const float4*>(inp + idx);
            tx = t4.x; ty = t4.y; tz = t4.z; tw = t4.w;
        }
        float4 mv = *reinterpret_cast<const float4*>(s_m + e * C_ + cq);
        float4 kv = *reinterpret_cast<const float4*>(s_k + e * C_ + cq);
        float fx = tx * mv.x - kv.x;
        float fy = ty * mv.y - kv.y;
        float fz = tz * mv.z - kv.z;
        float fw = tw * mv.w - kv.w;
        dx_[e] = fx; dy_[e] = fy; dz_[e] = fz; dw_[e] = fw;
        n0 += fabsf(fx); n1 += fabsf(fy); n2 += fabsf(fz); n3 += fabsf(fw);
        s0 += fx; s1 += fy; s2 += fz; s3 += fw;
    }

    const float inv9 = 1.0f / 9.0f;
    float m0 = s0 * inv9, m1 = s1 * inv9, m2 = s2 * inv9, m3 = s3 * inv9;

    float v0 = 0.f, v1 = 0.f, v2 = 0.f, v3 = 0.f;   // variation accum
#pragma unroll
    for (int e = 0; e < E; ++e) {
        v0 += fabsf(fabsf(dx_[e]) - m0);
        v1 += fabsf(fabsf(dy_[e]) - m1);
        v2 += fabsf(fabsf(dz_[e]) - m2);
        v3 += fabsf(fabsf(dw_[e]) - m3);
    }

    float4 o;
    o.x = (1.0f - v0 * inv9) * (1.0f - n0 * inv9);
    o.y = (1.0f - v1 * inv9) * (1.0f - n1 * inv9);
    o.z = (1.0f - v2 * inv9) * (1.0f - n2 * inv9);
    o.w = (1.0f - v3 * inv9) * (1.0f - n3 * inv9);

    *reinterpret_cast<float4*>(out + (size_t)gid * 4) = o;
}

extern "C" void kernel_launch(void* const* d_in, const int* in_sizes, int n_in,
                              void* d_out, int out_size, void* d_ws, size_t ws_size,
                              hipStream_t stream) {
    const float* inp  = (const float*)d_in[0];
    const float* kern = (const float*)d_in[1];
    const float* mask = (const float*)d_in[2];
    float* out = (float*)d_out;
    float* m   = (float*)d_ws;   // E*C_ floats = 1152 B

    fm_prep<<<1, 64, 0, stream>>>(mask, m);

    int nthreads = NTHREADS;
    int blocks = nthreads / 256;   // 12544, exact
    fm_main<<<blocks, 256, 0, stream>>>(inp, kern, m, out);
}

// Round 2
// 40.526 us; speedup vs baseline: 1.1507x; 1.1507x over previous
//
#include <hip/hip_runtime.h>

#define E  9
#define B_ 8
#define H_ 224
#define W_ 224
#define C_ 32
#define TH 8                       // output rows marched per thread
#define WT 32                      // w pixels per block
#define STRIPS (H_ / TH)           // 28
#define WTILES (W_ / WT)           // 7
#define NBLK (B_ * STRIPS * WTILES) // 1568 (divisible by 8 -> clean XCD swizzle)

__global__ __launch_bounds__(64) void fm_prep(const float* __restrict__ mask,
                                              float* __restrict__ m_out) {
    int t = threadIdx.x;           // single wave of 64
    float v[5];
    float mx = 0.0f;
#pragma unroll
    for (int i = 0; i < 5; ++i) {
        int idx = t + i * 64;
        v[i] = (idx < E * C_) ? fabsf(mask[idx]) : 0.0f;
        mx = fmaxf(mx, v[i]);
    }
#pragma unroll
    for (int off = 32; off >= 1; off >>= 1)
        mx = fmaxf(mx, __shfl_xor(mx, off));
    float inv = 1.0f / (mx + 1e-6f);
#pragma unroll
    for (int i = 0; i < 5; ++i) {
        int idx = t + i * 64;
        if (idx < E * C_) m_out[idx] = v[i] * inv;
    }
}

__global__ __launch_bounds__(256) void fm_main(const float* __restrict__ inp,
                                               const float* __restrict__ kern,
                                               const float* __restrict__ m,
                                               float* __restrict__ out) {
    __shared__ float s_m[E * C_];
    __shared__ float s_k[E * C_];
    for (int i = threadIdx.x; i < E * C_; i += 256) {
        s_m[i] = m[i];
        s_k[i] = kern[i];
    }
    __syncthreads();

    // Bijective XCD-chunk swizzle: each XCD gets one batch image (196 blocks).
    int bid = blockIdx.x;
    int swz = (bid & 7) * (NBLK / 8) + (bid >> 3);
    int bw  = swz % WTILES;
    int t2  = swz / WTILES;
    int hs  = (t2 % STRIPS) * TH;   // strip start row
    int b   = t2 / STRIPS;

    int t  = threadIdx.x;
    int cq = (t & 7) << 2;          // channel quad: 0,4,...,28
    int wl = t >> 3;                // 0..31
    int w  = bw * WT + wl;

    const float* base = inp + (((size_t)b * H_ * W_ + w) * C_) + cq;
    bool wm = (w > 0);
    bool wp = (w < W_ - 1);

    const float4 z4 = make_float4(0.f, 0.f, 0.f, 0.f);

    float4 win[3][3];   // [ring slot][x-offset -1,0,+1]

    auto ld3 = [&](int hh, float4* r) {
        if ((unsigned)hh < (unsigned)H_) {   // block-uniform branch
            const float* p = base + (size_t)hh * (W_ * C_);
            r[0] = wm ? *reinterpret_cast<const float4*>(p - C_) : z4;
            r[1] = *reinterpret_cast<const float4*>(p);
            r[2] = wp ? *reinterpret_cast<const float4*>(p + C_) : z4;
        } else {
            r[0] = z4; r[1] = z4; r[2] = z4;
        }
    };

    ld3(hs - 1, win[0]);
    ld3(hs,     win[1]);

    const float inv9 = 1.0f / 9.0f;

#pragma unroll
    for (int s = 0; s < TH; ++s) {
        ld3(hs + s + 1, win[(s + 2) % 3]);

        const float4* rm1 = win[(s + 0) % 3];   // row h-1
        const float4* r0  = win[(s + 1) % 3];   // row h
        const float4* rp1 = win[(s + 2) % 3];   // row h+1

        // tap order: e=0 center, then (y,x) raster skipping center
        float4 taps[E];
        taps[0] = r0[1];
        taps[1] = rm1[0]; taps[2] = rm1[1]; taps[3] = rm1[2];
        taps[4] = r0[0];  taps[5] = r0[2];
        taps[6] = rp1[0]; taps[7] = rp1[1]; taps[8] = rp1[2];

        float4 a[E];
        float n0 = 0.f, n1 = 0.f, n2 = 0.f, n3 = 0.f;
        float s0 = 0.f, s1 = 0.f, s2 = 0.f, s3 = 0.f;

#pragma unroll
        for (int e = 0; e < E; ++e) {
            float4 mv = *reinterpret_cast<const float4*>(s_m + e * C_ + cq);
            float4 kv = *reinterpret_cast<const float4*>(s_k + e * C_ + cq);
            float dx = fmaf(taps[e].x, mv.x, -kv.x);
            float dy = fmaf(taps[e].y, mv.y, -kv.y);
            float dz = fmaf(taps[e].z, mv.z, -kv.z);
            float dw = fmaf(taps[e].w, mv.w, -kv.w);
            a[e].x = fabsf(dx); a[e].y = fabsf(dy);
            a[e].z = fabsf(dz); a[e].w = fabsf(dw);
            n0 += a[e].x; n1 += a[e].y; n2 += a[e].z; n3 += a[e].w;
            s0 += dx; s1 += dy; s2 += dz; s3 += dw;
        }

        float m0 = s0 * inv9, m1 = s1 * inv9, m2 = s2 * inv9, m3 = s3 * inv9;

        float v0 = 0.f, v1 = 0.f, v2 = 0.f, v3 = 0.f;
#pragma unroll
        for (int e = 0; e < E; ++e) {
            v0 += fabsf(a[e].x - m0);
            v1 += fabsf(a[e].y - m1);
            v2 += fabsf(a[e].z - m2);
            v3 += fabsf(a[e].w - m3);
        }

        float4 o;
        o.x = (1.0f - v0 * inv9) * (1.0f - n0 * inv9);
        o.y = (1.0f - v1 * inv9) * (1.0f - n1 * inv9);
        o.z = (1.0f - v2 * inv9) * (1.0f - n2 * inv9);
        o.w = (1.0f - v3 * inv9) * (1.0f - n3 * inv9);

        float* op = out + (((size_t)b * H_ + (hs + s)) * W_ + w) * C_ + cq;
        *reinterpret_cast<float4*>(op) = o;
    }
}

extern "C" void kernel_launch(void* const* d_in, const int* in_sizes, int n_in,
                              void* d_out, int out_size, void* d_ws, size_t ws_size,
                              hipStream_t stream) {
    const float* inp  = (const float*)d_in[0];
    const float* kern = (const float*)d_in[1];
    const float* mask = (const float*)d_in[2];
    float* out = (float*)d_out;
    float* m   = (float*)d_ws;   // E*C_ floats = 1152 B

    fm_prep<<<1, 64, 0, stream>>>(mask, m);
    fm_main<<<NBLK, 256, 0, stream>>>(inp, kern, m, out);
}